// Round 1
// baseline (109.751 us; speedup 1.0000x reference)
//
#include <hip/hip_runtime.h>
#include <hip/hip_bf16.h>
#include <cstdint>

#define LN2F 0.69314718056f

// shifted softplus, numerically stable: softplus(x) - ln2
__device__ __forceinline__ float ssp(float x) {
    return fmaxf(x, 0.0f) + log1pf(expf(-fabsf(x))) - LN2F;
}

// ---------------------------------------------------------------------------
// Build filter table: T(d)[n] = ssp( ssp( rbf(d) @ W_s1 + b_s1 ) @ W_s2 + b_s2 )
// on grid d_g = g * 0.005, g in [0, 2048). Stored as packed bf16 pairs:
// P[g][t] = (lo = T[g][t], hi = T[g+1][t]) so one u32 load gives both lerp ends.
// ---------------------------------------------------------------------------
__global__ __launch_bounds__(256) void build_table_kernel(
    const float* __restrict__ W_s1, const float* __restrict__ b_s1,
    const float* __restrict__ W_s2, const float* __restrict__ b_s2,
    uint32_t* __restrict__ P) {
    __shared__ float rbf[4][304];
    __shared__ float hs[4][64];
    const int t = threadIdx.x;
    const int g0 = blockIdx.x * 4;

    // phase 1: RBF features (full 300, exact)
    for (int gg = 0; gg < 4; ++gg) {
        float d = (float)(g0 + gg) * 0.005f;
        for (int r = t; r < 300; r += 256) {
            float diff = d - 0.1f * (float)r;
            rbf[gg][r] = expf(-10.0f * diff * diff);
        }
    }
    __syncthreads();

    // phase 2: h = ssp(rbf @ W_s1 + b_s1)   (thread -> (gg, c))
    {
        int gg = t >> 6, c = t & 63;
        float acc = b_s1[c];
        for (int r = 0; r < 300; ++r)
            acc = fmaf(rbf[gg][r], W_s1[r * 64 + c], acc);
        hs[gg][c] = ssp(acc);
    }
    __syncthreads();

    // phase 3: T = ssp(h @ W_s2 + b_s2), pack bf16 pairs
    float val[4];
    {
        float b = b_s2[t];
        #pragma unroll
        for (int gg = 0; gg < 4; ++gg) val[gg] = b;
        for (int c = 0; c < 64; ++c) {
            float w = W_s2[c * 256 + t];
            #pragma unroll
            for (int gg = 0; gg < 4; ++gg)
                val[gg] = fmaf(hs[gg][c], w, val[gg]);
        }
    }
    __hip_bfloat16* Pb = (__hip_bfloat16*)P;
    for (int gg = 0; gg < 4; ++gg) {
        int g = g0 + gg;
        __hip_bfloat16 tv = __float2bfloat16(ssp(val[gg]));
        Pb[2 * (g * 256 + t)] = tv;                       // lo of P[g]   = T[g]
        if (g > 0) Pb[2 * ((g - 1) * 256 + t) + 1] = tv;  // hi of P[g-1] = T[g]
    }
}

// ---------------------------------------------------------------------------
// Generic linear layer over rows of [2048, 256]:
//   y[r,:] = act( (PREMASK ? x[r,:]*m[r] : x[r,:]) @ W + bias ) * m[r]
// 8 rows per block, LDS-staged (safe for in-place y == x).
// ---------------------------------------------------------------------------
template <int ACT, int PREMASK>
__global__ __launch_bounds__(256) void linear_kernel(
    const float* __restrict__ x, const float* __restrict__ W,
    const float* __restrict__ bias, const float* __restrict__ mask,
    float* __restrict__ y) {
    __shared__ float xs[8][256];
    const int t = threadIdx.x;
    const int r0 = blockIdx.x * 8;

    #pragma unroll
    for (int rr = 0; rr < 8; ++rr) {
        int r = r0 + rr;
        float v = x[r * 256 + t];
        if (PREMASK) v *= mask[r];  // mask flat [b*256+s] == row index
        xs[rr][t] = v;
    }
    __syncthreads();

    float acc[8];
    #pragma unroll
    for (int rr = 0; rr < 8; ++rr) acc[rr] = 0.0f;

    for (int k = 0; k < 256; k += 4) {
        float w0 = W[(k + 0) * 256 + t];
        float w1 = W[(k + 1) * 256 + t];
        float w2 = W[(k + 2) * 256 + t];
        float w3 = W[(k + 3) * 256 + t];
        #pragma unroll
        for (int rr = 0; rr < 8; ++rr) {
            float4 xv = *(const float4*)&xs[rr][k];
            float a = acc[rr];
            a = fmaf(xv.x, w0, a);
            a = fmaf(xv.y, w1, a);
            a = fmaf(xv.z, w2, a);
            a = fmaf(xv.w, w3, a);
            acc[rr] = a;
        }
    }

    float b = bias[t];
    #pragma unroll
    for (int rr = 0; rr < 8; ++rr) {
        int r = r0 + rr;
        float val = acc[rr] + b;
        if (ACT) val = ssp(val);
        y[r * 256 + t] = val * mask[r];
    }
}

// ---------------------------------------------------------------------------
// Main fused gather-sum: mid[b,i,d] = sum_j lerp(T, d_bij)[d] * v1[b,j,d]
// One block per (b,i); thread t owns output dim d = t.
// ---------------------------------------------------------------------------
__global__ __launch_bounds__(256) void gather_kernel(
    const float* __restrict__ dist, const float* __restrict__ v1,
    const uint32_t* __restrict__ P, float* __restrict__ mid) {
    __shared__ int sk[256];
    __shared__ float sf[256];
    const int t = threadIdx.x;
    const int bi = blockIdx.x;  // b*256 + i
    const int b = bi >> 8;

    // phase 0: per-j table index & fraction
    {
        float dd = dist[bi * 256 + t];
        float x = dd * 200.0f;  // 1/step, step = 0.005
        int k = (int)x;
        k = min(k, 2046);
        sk[t] = k;
        sf[t] = x - (float)k;
    }
    __syncthreads();

    const float* vbase = v1 + ((size_t)b << 16);
    float acc = 0.0f;
    #pragma unroll 4
    for (int j = 0; j < 256; ++j) {
        int k = sk[j];
        float f = sf[j];
        uint32_t u = P[(k << 8) + t];
        float lo = __uint_as_float(u << 16);
        float hi = __uint_as_float(u & 0xffff0000u);
        float w = fmaf(f, hi - lo, lo);
        acc = fmaf(w, vbase[(j << 8) + t], acc);
    }
    mid[bi * 256 + t] = acc;  // raw einsum; mask applied as premask downstream
}

// ---------------------------------------------------------------------------
extern "C" void kernel_launch(void* const* d_in, const int* in_sizes, int n_in,
                              void* d_out, int out_size, void* d_ws, size_t ws_size,
                              hipStream_t stream) {
    const float* v    = (const float*)d_in[0];
    const float* dist = (const float*)d_in[1];
    const float* mask = (const float*)d_in[2];
    const float* W_s1 = (const float*)d_in[3];
    const float* b_s1 = (const float*)d_in[4];
    const float* W_s2 = (const float*)d_in[5];
    const float* b_s2 = (const float*)d_in[6];
    const float* W_a1 = (const float*)d_in[7];
    const float* b_a1 = (const float*)d_in[8];
    const float* W_a2 = (const float*)d_in[9];
    const float* b_a2 = (const float*)d_in[10];
    const float* W_a3 = (const float*)d_in[11];
    const float* b_a3 = (const float*)d_in[12];
    float* out = (float*)d_out;

    char* ws = (char*)d_ws;
    float*    v1  = (float*)(ws);                  // 2 MB: masked atom_wise_1 output
    float*    mid = (float*)(ws + (2u << 20));     // 2 MB: raw einsum output
    uint32_t* P   = (uint32_t*)(ws + (4u << 20));  // 2 MB: packed bf16 filter table

    // v1 = ((v*m) @ W_a1 + b_a1) * m
    linear_kernel<0, 1><<<256, 256, 0, stream>>>(v, W_a1, b_a1, mask, v1);
    // filter table
    build_table_kernel<<<512, 256, 0, stream>>>(W_s1, b_s1, W_s2, b_s2, P);
    // mid = einsum('bjd,bijd->bid', v1, F(dist))
    gather_kernel<<<2048, 256, 0, stream>>>(dist, v1, P, mid);
    // out = ssp((mid*m) @ W_a2 + b_a2) * m
    linear_kernel<1, 1><<<256, 256, 0, stream>>>(mid, W_a2, b_a2, mask, out);
    // out = (out @ W_a3 + b_a3) * m   (in-place safe: rows staged to LDS first)
    linear_kernel<0, 0><<<256, 256, 0, stream>>>(out, W_a3, b_a3, mask, out);
}

// Round 2
// 90.143 us; speedup vs baseline: 1.2175x; 1.2175x over previous
//
#include <hip/hip_runtime.h>
#include <hip/hip_bf16.h>
#include <cstdint>

#define LN2F 0.69314718056f

// shifted softplus, numerically stable: softplus(x) - ln2
__device__ __forceinline__ float ssp(float x) {
    return fmaxf(x, 0.0f) + log1pf(expf(-fabsf(x))) - LN2F;
}

// round-to-nearest-even f32 -> bf16 bits
__device__ __forceinline__ uint16_t f2bf_rne(float x) {
    uint32_t u = __float_as_uint(x);
    u += 0x7FFF + ((u >> 16) & 1u);
    return (uint16_t)(u >> 16);
}

// ---------------------------------------------------------------------------
// Kernel A (prep): role-split on blockIdx.
//   blocks [0,256):  v1 = ((v*m) @ W_a1 + b_a1) * m        (8 rows/block)
//   blocks [256,768): filter table T[g][d] = F(g*0.0025)[d] as bf16 (8 g/block)
// F(d) = ssp( ssp(rbf(d) @ W_s1 + b_s1) @ W_s2 + b_s2 ), nearest-neighbor use.
// ---------------------------------------------------------------------------
__global__ __launch_bounds__(512) void prep_kernel(
    const float* __restrict__ v, const float* __restrict__ mask,
    const float* __restrict__ W_a1, const float* __restrict__ b_a1,
    const float* __restrict__ W_s1, const float* __restrict__ b_s1,
    const float* __restrict__ W_s2, const float* __restrict__ b_s2,
    float* __restrict__ v1, uint16_t* __restrict__ T) {
    __shared__ float sA[8][304];   // linear: x rows [8][256] ; build: rbf [8][300]
    __shared__ float sB[8][64];    // build: h layer
    const int t = threadIdx.x;

    if (blockIdx.x < 256) {
        // ----- linear role: 8 rows, 2 col-groups x 4 rows each -----
        const int r0 = blockIdx.x * 8;
        for (int e = t; e < 2048; e += 512) {
            int row = e >> 8, c = e & 255;
            sA[row][c] = v[(r0 + row) * 256 + c] * mask[r0 + row];
        }
        __syncthreads();
        const int g = t >> 8;      // 0/1 -> rows 4g..4g+3
        const int col = t & 255;
        float acc[4] = {0.f, 0.f, 0.f, 0.f};
        for (int k = 0; k < 256; k += 4) {
            float w0 = W_a1[(k + 0) * 256 + col];
            float w1 = W_a1[(k + 1) * 256 + col];
            float w2 = W_a1[(k + 2) * 256 + col];
            float w3 = W_a1[(k + 3) * 256 + col];
            #pragma unroll
            for (int rr = 0; rr < 4; ++rr) {
                const float4 xv = *(const float4*)&sA[g * 4 + rr][k];
                float a = acc[rr];
                a = fmaf(xv.x, w0, a);
                a = fmaf(xv.y, w1, a);
                a = fmaf(xv.z, w2, a);
                a = fmaf(xv.w, w3, a);
                acc[rr] = a;
            }
        }
        float b = b_a1[col];
        #pragma unroll
        for (int rr = 0; rr < 4; ++rr) {
            int r = r0 + g * 4 + rr;
            v1[r * 256 + col] = (acc[rr] + b) * mask[r];
        }
    } else {
        // ----- table-build role: 8 grid points per block -----
        const int g0 = (blockIdx.x - 256) * 8;
        #pragma unroll
        for (int gg = 0; gg < 8; ++gg) {
            if (t < 300) {
                float d = (float)(g0 + gg) * 0.0025f;
                float diff = d - 0.1f * (float)t;
                sA[gg][t] = expf(-10.f * diff * diff);
            }
        }
        __syncthreads();
        {   // h = ssp(rbf @ W_s1 + b_s1): thread -> (gg = t>>6, c = t&63)
            int gg = t >> 6, c = t & 63;
            float acc = b_s1[c];
            for (int r = 0; r < 300; ++r)
                acc = fmaf(sA[gg][r], W_s1[r * 64 + c], acc);
            sB[gg][c] = ssp(acc);
        }
        __syncthreads();
        {   // T = ssp(h @ W_s2 + b_s2): thread -> col = t&255, glo = t>>8, 4 gg each
            int col = t & 255, glo = t >> 8;
            float bb = b_s2[col];
            float val[4];
            #pragma unroll
            for (int q = 0; q < 4; ++q) val[q] = bb;
            for (int c = 0; c < 64; ++c) {
                float w = W_s2[c * 256 + col];
                #pragma unroll
                for (int q = 0; q < 4; ++q)
                    val[q] = fmaf(sB[glo + 2 * q][c], w, val[q]);
            }
            #pragma unroll
            for (int q = 0; q < 4; ++q) {
                int g = g0 + glo + 2 * q;
                T[g * 256 + col] = f2bf_rne(ssp(val[q]));
            }
        }
    }
}

// ---------------------------------------------------------------------------
// Kernel B (gather): mid[b,i,d] = sum_j T[round(d_bij/h)][d] * v1[b,j,d]
// Block = 512 thr, 4 rows (same b). h = t>>7 row, p = t&127 dim-pair (2 dims).
// v1 tiled through LDS (reuse x4); table rows NN-indexed, 2B/dim.
// ---------------------------------------------------------------------------
__global__ __launch_bounds__(512) void gather_kernel(
    const float* __restrict__ dist, const float* __restrict__ v1,
    const uint16_t* __restrict__ T, float* __restrict__ mid) {
    __shared__ float v1s[32][256];     // 32 KB j-tile
    __shared__ uint32_t sk[4][256];    // per-row table byte offsets
    const int t = threadIdx.x;
    const int r0 = blockIdx.x * 4;     // global row (b*256+i), 4 per block
    const int b = r0 >> 8;
    const int h = t >> 7;              // which of the 4 rows
    const int p = t & 127;             // dim pair -> d = 2p, 2p+1

    for (int e = t; e < 1024; e += 512) {
        int row = e >> 8, j = e & 255;
        float d = dist[(r0 + row) * 256 + j];
        int k = (int)fmaf(d, 400.f, 0.5f);   // nearest grid point, h = 0.0025
        k = min(k, 4095);
        sk[row][j] = (uint32_t)(k << 9);     // byte offset: 256 dims * 2B = 512B/row
    }

    float acc0 = 0.f, acc1 = 0.f;
    const char* Tp = (const char*)T + (p << 2);

    for (int jt = 0; jt < 256; jt += 32) {
        __syncthreads();                     // (also covers sk on first iter)
        const float4* src = (const float4*)(v1 + ((size_t)b << 16) + (size_t)jt * 256);
        float4* dst = (float4*)v1s;
        #pragma unroll
        for (int u = 0; u < 4; ++u)
            dst[u * 512 + t] = src[u * 512 + t];
        __syncthreads();

        #pragma unroll 2
        for (int jj = 0; jj < 32; jj += 4) {
            const uint4 kk = *(const uint4*)&sk[h][jt + jj];
            uint32_t u0 = *(const uint32_t*)(Tp + kk.x);
            uint32_t u1 = *(const uint32_t*)(Tp + kk.y);
            uint32_t u2 = *(const uint32_t*)(Tp + kk.z);
            uint32_t u3 = *(const uint32_t*)(Tp + kk.w);
            float2 vv0 = *(const float2*)&v1s[jj + 0][p * 2];
            float2 vv1 = *(const float2*)&v1s[jj + 1][p * 2];
            float2 vv2 = *(const float2*)&v1s[jj + 2][p * 2];
            float2 vv3 = *(const float2*)&v1s[jj + 3][p * 2];
            acc0 = fmaf(__uint_as_float(u0 << 16), vv0.x, acc0);
            acc1 = fmaf(__uint_as_float(u0 & 0xffff0000u), vv0.y, acc1);
            acc0 = fmaf(__uint_as_float(u1 << 16), vv1.x, acc0);
            acc1 = fmaf(__uint_as_float(u1 & 0xffff0000u), vv1.y, acc1);
            acc0 = fmaf(__uint_as_float(u2 << 16), vv2.x, acc0);
            acc1 = fmaf(__uint_as_float(u2 & 0xffff0000u), vv2.y, acc1);
            acc0 = fmaf(__uint_as_float(u3 << 16), vv3.x, acc0);
            acc1 = fmaf(__uint_as_float(u3 & 0xffff0000u), vv3.y, acc1);
        }
    }
    const int r = r0 + h;
    *(float2*)&mid[r * 256 + 2 * p] = make_float2(acc0, acc1);
}

// ---------------------------------------------------------------------------
// Kernel C (fused a2+a3): per block of 8 rows:
//   y = ssp((mid*m) @ W_a2 + b_a2) * m   (kept in LDS)
//   out = (y @ W_a3 + b_a3) * m
// ---------------------------------------------------------------------------
__global__ __launch_bounds__(512) void out_kernel(
    const float* __restrict__ mid, const float* __restrict__ mask,
    const float* __restrict__ W_a2, const float* __restrict__ b_a2,
    const float* __restrict__ W_a3, const float* __restrict__ b_a3,
    float* __restrict__ out) {
    __shared__ float xs[8][256];
    const int t = threadIdx.x;
    const int r0 = blockIdx.x * 8;
    const int g = t >> 8;     // 0/1 -> rows 4g..4g+3
    const int col = t & 255;

    for (int e = t; e < 2048; e += 512) {
        int row = e >> 8, c = e & 255;
        xs[row][c] = mid[(r0 + row) * 256 + c] * mask[r0 + row];
    }
    __syncthreads();

    float acc[4] = {0.f, 0.f, 0.f, 0.f};
    for (int k = 0; k < 256; k += 4) {
        float w0 = W_a2[(k + 0) * 256 + col];
        float w1 = W_a2[(k + 1) * 256 + col];
        float w2 = W_a2[(k + 2) * 256 + col];
        float w3 = W_a2[(k + 3) * 256 + col];
        #pragma unroll
        for (int rr = 0; rr < 4; ++rr) {
            const float4 xv = *(const float4*)&xs[g * 4 + rr][k];
            float a = acc[rr];
            a = fmaf(xv.x, w0, a);
            a = fmaf(xv.y, w1, a);
            a = fmaf(xv.z, w2, a);
            a = fmaf(xv.w, w3, a);
            acc[rr] = a;
        }
    }
    float b2 = b_a2[col];
    float y[4];
    #pragma unroll
    for (int rr = 0; rr < 4; ++rr)
        y[rr] = ssp(acc[rr] + b2) * mask[r0 + g * 4 + rr];

    __syncthreads();   // everyone done reading xs
    #pragma unroll
    for (int rr = 0; rr < 4; ++rr) xs[g * 4 + rr][col] = y[rr];
    __syncthreads();

    float acc2[4] = {0.f, 0.f, 0.f, 0.f};
    for (int k = 0; k < 256; k += 4) {
        float w0 = W_a3[(k + 0) * 256 + col];
        float w1 = W_a3[(k + 1) * 256 + col];
        float w2 = W_a3[(k + 2) * 256 + col];
        float w3 = W_a3[(k + 3) * 256 + col];
        #pragma unroll
        for (int rr = 0; rr < 4; ++rr) {
            const float4 xv = *(const float4*)&xs[g * 4 + rr][k];
            float a = acc2[rr];
            a = fmaf(xv.x, w0, a);
            a = fmaf(xv.y, w1, a);
            a = fmaf(xv.z, w2, a);
            a = fmaf(xv.w, w3, a);
            acc2[rr] = a;
        }
    }
    float b3 = b_a3[col];
    #pragma unroll
    for (int rr = 0; rr < 4; ++rr) {
        int r = r0 + g * 4 + rr;
        out[r * 256 + col] = (acc2[rr] + b3) * mask[r];
    }
}

// ---------------------------------------------------------------------------
extern "C" void kernel_launch(void* const* d_in, const int* in_sizes, int n_in,
                              void* d_out, int out_size, void* d_ws, size_t ws_size,
                              hipStream_t stream) {
    const float* v    = (const float*)d_in[0];
    const float* dist = (const float*)d_in[1];
    const float* mask = (const float*)d_in[2];
    const float* W_s1 = (const float*)d_in[3];
    const float* b_s1 = (const float*)d_in[4];
    const float* W_s2 = (const float*)d_in[5];
    const float* b_s2 = (const float*)d_in[6];
    const float* W_a1 = (const float*)d_in[7];
    const float* b_a1 = (const float*)d_in[8];
    const float* W_a2 = (const float*)d_in[9];
    const float* b_a2 = (const float*)d_in[10];
    const float* W_a3 = (const float*)d_in[11];
    const float* b_a3 = (const float*)d_in[12];
    float* out = (float*)d_out;

    char* ws = (char*)d_ws;
    float*    v1  = (float*)(ws);                   // 2 MB
    float*    mid = (float*)(ws + (2u << 20));      // 2 MB
    uint16_t* T   = (uint16_t*)(ws + (4u << 20));   // 2 MB: bf16 table [4096][256]

    prep_kernel<<<768, 512, 0, stream>>>(v, mask, W_a1, b_a1, W_s1, b_s1, W_s2, b_s2, v1, T);
    gather_kernel<<<512, 512, 0, stream>>>(dist, v1, T, mid);
    out_kernel<<<256, 512, 0, stream>>>(mid, mask, W_a2, b_a2, W_a3, b_a3, out);
}

// Round 3
// 81.333 us; speedup vs baseline: 1.3494x; 1.1083x over previous
//
#include <hip/hip_runtime.h>
#include <hip/hip_bf16.h>
#include <cstdint>

#define LN2F 0.69314718056f

__device__ __forceinline__ float ssp(float x) {
    return fmaxf(x, 0.0f) + log1pf(expf(-fabsf(x))) - LN2F;
}

__device__ __forceinline__ uint16_t f2bf_rne(float x) {
    uint32_t u = __float_as_uint(x);
    u += 0x7FFF + ((u >> 16) & 1u);
    return (uint16_t)(u >> 16);
}

// ---------------------------------------------------------------------------
// Filter table: T[g][d] = F(g*0.0025)[d] bf16, nearest-neighbor use (4096 pts).
// F(d) = ssp( ssp(rbf(d) @ W_s1 + b_s1) @ W_s2 + b_s2 )
// ---------------------------------------------------------------------------
__global__ __launch_bounds__(512) void table_kernel(
    const float* __restrict__ W_s1, const float* __restrict__ b_s1,
    const float* __restrict__ W_s2, const float* __restrict__ b_s2,
    uint16_t* __restrict__ T) {
    __shared__ float sA[8][304];
    __shared__ float sB[8][64];
    const int t = threadIdx.x;
    const int g0 = blockIdx.x * 8;

    #pragma unroll
    for (int gg = 0; gg < 8; ++gg) {
        if (t < 300) {
            float d = (float)(g0 + gg) * 0.0025f;
            float diff = d - 0.1f * (float)t;
            sA[gg][t] = expf(-10.f * diff * diff);
        }
    }
    __syncthreads();
    {   // h = ssp(rbf @ W_s1 + b_s1): thread -> (gg = t>>6, c = t&63)
        int gg = t >> 6, c = t & 63;
        float acc = b_s1[c];
        for (int r = 0; r < 300; ++r)
            acc = fmaf(sA[gg][r], W_s1[r * 64 + c], acc);
        sB[gg][c] = ssp(acc);
    }
    __syncthreads();
    {   // T = ssp(h @ W_s2 + b_s2): col = t&255, glo = t>>8, 4 gg each
        int col = t & 255, glo = t >> 8;
        float bb = b_s2[col];
        float val[4];
        #pragma unroll
        for (int q = 0; q < 4; ++q) val[q] = bb;
        for (int c = 0; c < 64; ++c) {
            float w = W_s2[c * 256 + col];
            #pragma unroll
            for (int q = 0; q < 4; ++q)
                val[q] = fmaf(sB[glo + 2 * q][c], w, val[q]);
        }
        #pragma unroll
        for (int q = 0; q < 4; ++q) {
            int g = g0 + glo + 2 * q;
            T[g * 256 + col] = f2bf_rne(ssp(val[q]));
        }
    }
}

// ---------------------------------------------------------------------------
// Linear over rows of [2048,256]: y[r,c] = post( pre(x[r,:]@W)[c] ) * m[r]
//   PRE=1:  a = (x@W)*m[r] + b   (equivalent to premasking x rows)
//   ACT=1:  a = ssp(a)
// 4 rows/block, 512 blocks (2/CU). x read as wave-uniform broadcast float4
// (L1/L2, no LDS). W streamed coalesced with 16-deep register pipeline and
// per-block k-phase rotation (de-hotspots L2).
// ---------------------------------------------------------------------------
template <int ACT, int PRE>
__global__ __launch_bounds__(256) void lin_kernel(
    const float* __restrict__ x, const float* __restrict__ W,
    const float* __restrict__ bias, const float* __restrict__ mask,
    float* __restrict__ y) {
    const int col = threadIdx.x;
    const int r0 = blockIdx.x * 4;
    const int c0 = blockIdx.x & 15;

    float acc0 = 0.f, acc1 = 0.f, acc2 = 0.f, acc3 = 0.f;
    float w[16], wn[16];
    {
        const int kt = c0 * 16;
        #pragma unroll
        for (int q = 0; q < 16; ++q) w[q] = W[(kt + q) * 256 + col];
    }
    #pragma unroll 2
    for (int i = 0; i < 16; ++i) {
        const int kt  = ((c0 + i) & 15) * 16;
        const int ktn = ((c0 + i + 1) & 15) * 16;
        if (i < 15) {
            #pragma unroll
            for (int q = 0; q < 16; ++q) wn[q] = W[(ktn + q) * 256 + col];
        }
        #pragma unroll
        for (int q4 = 0; q4 < 4; ++q4) {
            const int k = kt + q4 * 4;
            const float4 x0 = *(const float4*)&x[(r0 + 0) * 256 + k];
            const float4 x1 = *(const float4*)&x[(r0 + 1) * 256 + k];
            const float4 x2 = *(const float4*)&x[(r0 + 2) * 256 + k];
            const float4 x3 = *(const float4*)&x[(r0 + 3) * 256 + k];
            const float w0 = w[q4 * 4 + 0], w1 = w[q4 * 4 + 1];
            const float w2 = w[q4 * 4 + 2], w3 = w[q4 * 4 + 3];
            acc0 = fmaf(x0.x, w0, acc0); acc0 = fmaf(x0.y, w1, acc0);
            acc0 = fmaf(x0.z, w2, acc0); acc0 = fmaf(x0.w, w3, acc0);
            acc1 = fmaf(x1.x, w0, acc1); acc1 = fmaf(x1.y, w1, acc1);
            acc1 = fmaf(x1.z, w2, acc1); acc1 = fmaf(x1.w, w3, acc1);
            acc2 = fmaf(x2.x, w0, acc2); acc2 = fmaf(x2.y, w1, acc2);
            acc2 = fmaf(x2.z, w2, acc2); acc2 = fmaf(x2.w, w3, acc2);
            acc3 = fmaf(x3.x, w0, acc3); acc3 = fmaf(x3.y, w1, acc3);
            acc3 = fmaf(x3.z, w2, acc3); acc3 = fmaf(x3.w, w3, acc3);
        }
        if (i < 15) {
            #pragma unroll
            for (int q = 0; q < 16; ++q) w[q] = wn[q];
        }
    }

    const float b = bias[col];
    float accs[4] = {acc0, acc1, acc2, acc3};
    #pragma unroll
    for (int rr = 0; rr < 4; ++rr) {
        const int r = r0 + rr;
        const float mval = mask[r];
        float a = accs[rr];
        if (PRE) a *= mval;
        a += b;
        if (ACT) a = ssp(a);
        y[r * 256 + col] = a * mval;
    }
}

// ---------------------------------------------------------------------------
// Gather: mid[b,i,d] = sum_j T[round(d_bij/h)][d] * v1[b,j,d]
// Block = 512 thr, 4 rows (same b). v1 tiled through LDS; table NN rows.
// ---------------------------------------------------------------------------
__global__ __launch_bounds__(512) void gather_kernel(
    const float* __restrict__ dist, const float* __restrict__ v1,
    const uint16_t* __restrict__ T, float* __restrict__ mid) {
    __shared__ float v1s[32][256];
    __shared__ uint32_t sk[4][256];
    const int t = threadIdx.x;
    const int r0 = blockIdx.x * 4;
    const int b = r0 >> 8;
    const int h = t >> 7;
    const int p = t & 127;

    for (int e = t; e < 1024; e += 512) {
        int row = e >> 8, j = e & 255;
        float d = dist[(r0 + row) * 256 + j];
        int k = (int)fmaf(d, 400.f, 0.5f);
        k = min(k, 4095);
        sk[row][j] = (uint32_t)(k << 9);
    }

    float acc0 = 0.f, acc1 = 0.f;
    const char* Tp = (const char*)T + (p << 2);

    for (int jt = 0; jt < 256; jt += 32) {
        __syncthreads();
        const float4* src = (const float4*)(v1 + ((size_t)b << 16) + (size_t)jt * 256);
        float4* dst = (float4*)v1s;
        #pragma unroll
        for (int u = 0; u < 4; ++u)
            dst[u * 512 + t] = src[u * 512 + t];
        __syncthreads();

        #pragma unroll 2
        for (int jj = 0; jj < 32; jj += 4) {
            const uint4 kk = *(const uint4*)&sk[h][jt + jj];
            uint32_t u0 = *(const uint32_t*)(Tp + kk.x);
            uint32_t u1 = *(const uint32_t*)(Tp + kk.y);
            uint32_t u2 = *(const uint32_t*)(Tp + kk.z);
            uint32_t u3 = *(const uint32_t*)(Tp + kk.w);
            float2 vv0 = *(const float2*)&v1s[jj + 0][p * 2];
            float2 vv1 = *(const float2*)&v1s[jj + 1][p * 2];
            float2 vv2 = *(const float2*)&v1s[jj + 2][p * 2];
            float2 vv3 = *(const float2*)&v1s[jj + 3][p * 2];
            acc0 = fmaf(__uint_as_float(u0 << 16), vv0.x, acc0);
            acc1 = fmaf(__uint_as_float(u0 & 0xffff0000u), vv0.y, acc1);
            acc0 = fmaf(__uint_as_float(u1 << 16), vv1.x, acc0);
            acc1 = fmaf(__uint_as_float(u1 & 0xffff0000u), vv1.y, acc1);
            acc0 = fmaf(__uint_as_float(u2 << 16), vv2.x, acc0);
            acc1 = fmaf(__uint_as_float(u2 & 0xffff0000u), vv2.y, acc1);
            acc0 = fmaf(__uint_as_float(u3 << 16), vv3.x, acc0);
            acc1 = fmaf(__uint_as_float(u3 & 0xffff0000u), vv3.y, acc1);
        }
    }
    const int r = r0 + h;
    *(float2*)&mid[r * 256 + 2 * p] = make_float2(acc0, acc1);
}

// ---------------------------------------------------------------------------
extern "C" void kernel_launch(void* const* d_in, const int* in_sizes, int n_in,
                              void* d_out, int out_size, void* d_ws, size_t ws_size,
                              hipStream_t stream) {
    const float* v    = (const float*)d_in[0];
    const float* dist = (const float*)d_in[1];
    const float* mask = (const float*)d_in[2];
    const float* W_s1 = (const float*)d_in[3];
    const float* b_s1 = (const float*)d_in[4];
    const float* W_s2 = (const float*)d_in[5];
    const float* b_s2 = (const float*)d_in[6];
    const float* W_a1 = (const float*)d_in[7];
    const float* b_a1 = (const float*)d_in[8];
    const float* W_a2 = (const float*)d_in[9];
    const float* b_a2 = (const float*)d_in[10];
    const float* W_a3 = (const float*)d_in[11];
    const float* b_a3 = (const float*)d_in[12];
    float* out = (float*)d_out;

    char* ws = (char*)d_ws;
    float*    v1  = (float*)(ws);                   // 2 MB
    float*    mid = (float*)(ws + (2u << 20));      // 2 MB
    uint16_t* T   = (uint16_t*)(ws + (4u << 20));   // 2 MB bf16 [4096][256]
    float*    y2  = (float*)(ws + (6u << 20));      // 2 MB

    lin_kernel<0, 1><<<512, 256, 0, stream>>>(v, W_a1, b_a1, mask, v1);
    table_kernel<<<512, 512, 0, stream>>>(W_s1, b_s1, W_s2, b_s2, T);
    gather_kernel<<<512, 512, 0, stream>>>(dist, v1, T, mid);
    lin_kernel<1, 1><<<512, 256, 0, stream>>>(mid, W_a2, b_a2, mask, y2);
    lin_kernel<0, 0><<<512, 256, 0, stream>>>(y2, W_a3, b_a3, mask, out);
}

// Round 4
// 75.257 us; speedup vs baseline: 1.4583x; 1.0807x over previous
//
#include <hip/hip_runtime.h>
#include <hip/hip_bf16.h>
#include <cstdint>

#define LN2F 0.69314718056f

__device__ __forceinline__ float ssp(float x) {
    return fmaxf(x, 0.0f) + log1pf(expf(-fabsf(x))) - LN2F;
}

__device__ __forceinline__ uint16_t f2bf_rne(float x) {
    uint32_t u = __float_as_uint(x);
    u += 0x7FFF + ((u >> 16) & 1u);
    return (uint16_t)(u >> 16);
}

__device__ __forceinline__ float bf_lo(uint32_t u) { return __uint_as_float(u << 16); }
__device__ __forceinline__ float bf_hi(uint32_t u) { return __uint_as_float(u & 0xffff0000u); }

// ---------------------------------------------------------------------------
// prep: blocks [0,256): v1 = (m*(v@W_a1) + b_a1) * m   (8 rows/block)
//       blocks [256,768): filter table T[g][d] = F(g*0.0025)[d] bf16 (8 g/block)
// F(d) = ssp( ssp(rbf(d) @ W_s1 + b_s1) @ W_s2 + b_s2 )
// ---------------------------------------------------------------------------
__global__ __launch_bounds__(512) void prep_kernel(
    const float* __restrict__ v, const float* __restrict__ mask,
    const float* __restrict__ W_a1, const float* __restrict__ b_a1,
    const float* __restrict__ W_s1, const float* __restrict__ b_s1,
    const float* __restrict__ W_s2, const float* __restrict__ b_s2,
    float* __restrict__ v1, uint16_t* __restrict__ T) {
    __shared__ float sA[8][304];   // lin: x rows [8][256]; table: rbf [8][300]
    __shared__ float sB[8][64];    // table: hidden layer
    const int t = threadIdx.x;

    if (blockIdx.x < 256) {
        // ---------------- linear role ----------------
        const int r0 = blockIdx.x * 8;
        for (int e = t; e < 2048; e += 512) {
            int row = e >> 8, c = e & 255;
            sA[row][c] = v[(r0 + row) * 256 + c];
        }
        __syncthreads();
        const int col = t & 255;
        const int g = t >> 8;             // rows 4g..4g+3
        const int c0 = blockIdx.x & 15;   // k-phase rotation
        float acc[4] = {0.f, 0.f, 0.f, 0.f};
        float w[16], wn[16];
        {
            const int kt = c0 * 16;
            #pragma unroll
            for (int q = 0; q < 16; ++q) w[q] = W_a1[(kt + q) * 256 + col];
        }
        for (int i = 0; i < 16; ++i) {
            const int kt = ((c0 + i) & 15) * 16;
            if (i < 15) {
                const int ktn = ((c0 + i + 1) & 15) * 16;
                #pragma unroll
                for (int q = 0; q < 16; ++q) wn[q] = W_a1[(ktn + q) * 256 + col];
            }
            #pragma unroll
            for (int q4 = 0; q4 < 4; ++q4) {
                const int k = kt + q4 * 4;
                const float w0 = w[q4 * 4 + 0], w1 = w[q4 * 4 + 1];
                const float w2 = w[q4 * 4 + 2], w3 = w[q4 * 4 + 3];
                #pragma unroll
                for (int rr = 0; rr < 4; ++rr) {
                    const float4 xv = *(const float4*)&sA[g * 4 + rr][k];
                    float a = acc[rr];
                    a = fmaf(xv.x, w0, a);
                    a = fmaf(xv.y, w1, a);
                    a = fmaf(xv.z, w2, a);
                    a = fmaf(xv.w, w3, a);
                    acc[rr] = a;
                }
            }
            if (i < 15) {
                #pragma unroll
                for (int q = 0; q < 16; ++q) w[q] = wn[q];
            }
        }
        const float b = b_a1[col];
        #pragma unroll
        for (int rr = 0; rr < 4; ++rr) {
            const int r = r0 + g * 4 + rr;
            const float m = mask[r];
            v1[r * 256 + col] = (acc[rr] * m + b) * m;
        }
    } else {
        // ---------------- table role ----------------
        const int g0 = (blockIdx.x - 256) * 8;
        #pragma unroll
        for (int gg = 0; gg < 8; ++gg) {
            if (t < 300) {
                float d = (float)(g0 + gg) * 0.0025f;
                float diff = d - 0.1f * (float)t;
                sA[gg][t] = expf(-10.f * diff * diff);
            }
        }
        __syncthreads();
        {   // h = ssp(rbf @ W_s1 + b_s1)
            int gg = t >> 6, c = t & 63;
            float acc = b_s1[c];
            for (int r = 0; r < 300; ++r)
                acc = fmaf(sA[gg][r], W_s1[r * 64 + c], acc);
            sB[gg][c] = ssp(acc);
        }
        __syncthreads();
        {   // T = ssp(h @ W_s2 + b_s2)
            int col = t & 255, glo = t >> 8;
            float bb = b_s2[col];
            float val[4];
            #pragma unroll
            for (int q = 0; q < 4; ++q) val[q] = bb;
            for (int c = 0; c < 64; ++c) {
                float w = W_s2[c * 256 + col];
                #pragma unroll
                for (int q = 0; q < 4; ++q)
                    val[q] = fmaf(sB[glo + 2 * q][c], w, val[q]);
            }
            #pragma unroll
            for (int q = 0; q < 4; ++q) {
                int g = g0 + glo + 2 * q;
                T[g * 256 + col] = f2bf_rne(ssp(val[q]));
            }
        }
    }
}

// ---------------------------------------------------------------------------
// main: per block of 8 rows (256 blocks, 512 thr):
//   mid[r,:] = sum_j T[round(d/h)][:] * v1[b,j,:]     (v1 LDS-tiled)
//   y  = ssp((mid*m) @ W_a2 + b_a2) * m               (mid*m kept in LDS)
//   out = (y @ W_a3 + b_a3) * m                       (y kept in LDS)
// Gather layout: h = t>>6 row (wave-uniform), p = t&63 owns dims 4p..4p+3.
// ---------------------------------------------------------------------------
__global__ __launch_bounds__(512) void main_kernel(
    const float* __restrict__ dist, const float* __restrict__ v1,
    const uint16_t* __restrict__ T, const float* __restrict__ mask,
    const float* __restrict__ W_a2, const float* __restrict__ b_a2,
    const float* __restrict__ W_a3, const float* __restrict__ b_a3,
    float* __restrict__ out) {
    __shared__ float v1s[32][256];     // 32 KB j-tile
    __shared__ uint32_t sk[8][256];    // 8 KB table byte offsets
    __shared__ float xs[8][256];       // 8 KB activation rows
    const int t = threadIdx.x;
    const int r0 = blockIdx.x * 8;
    const int b = r0 >> 8;
    const int h = t >> 6;              // row within block (wave-uniform)
    const int p = t & 63;              // dim group: dims 4p..4p+3

    for (int e = t; e < 2048; e += 512) {
        int row = e >> 8, j = e & 255;
        float d = dist[(r0 + row) * 256 + j];
        int k = (int)fmaf(d, 400.f, 0.5f);     // nearest grid point, step 0.0025
        k = min(k, 4095);
        sk[row][j] = (uint32_t)(k << 9);       // byte offset (512 B/row)
    }

    float a0 = 0.f, a1 = 0.f, a2 = 0.f, a3 = 0.f;
    const char* Tp = (const char*)T + (p << 3);

    for (int jt = 0; jt < 256; jt += 32) {
        __syncthreads();                       // first iter also covers sk
        const float4* src = (const float4*)(v1 + ((size_t)b << 16) + (size_t)jt * 256);
        float4* dst = (float4*)v1s;
        #pragma unroll
        for (int u = 0; u < 4; ++u)
            dst[u * 512 + t] = src[u * 512 + t];
        __syncthreads();

        #pragma unroll 2
        for (int jj = 0; jj < 32; jj += 4) {
            const uint4 kk = *(const uint4*)&sk[h][jt + jj];
            const uint2 u0 = *(const uint2*)(Tp + kk.x);
            const uint2 u1 = *(const uint2*)(Tp + kk.y);
            const uint2 u2 = *(const uint2*)(Tp + kk.z);
            const uint2 u3 = *(const uint2*)(Tp + kk.w);
            const float4 w0 = *(const float4*)&v1s[jj + 0][p * 4];
            const float4 w1 = *(const float4*)&v1s[jj + 1][p * 4];
            const float4 w2 = *(const float4*)&v1s[jj + 2][p * 4];
            const float4 w3 = *(const float4*)&v1s[jj + 3][p * 4];
            a0 = fmaf(bf_lo(u0.x), w0.x, a0);
            a1 = fmaf(bf_hi(u0.x), w0.y, a1);
            a2 = fmaf(bf_lo(u0.y), w0.z, a2);
            a3 = fmaf(bf_hi(u0.y), w0.w, a3);
            a0 = fmaf(bf_lo(u1.x), w1.x, a0);
            a1 = fmaf(bf_hi(u1.x), w1.y, a1);
            a2 = fmaf(bf_lo(u1.y), w1.z, a2);
            a3 = fmaf(bf_hi(u1.y), w1.w, a3);
            a0 = fmaf(bf_lo(u2.x), w2.x, a0);
            a1 = fmaf(bf_hi(u2.x), w2.y, a1);
            a2 = fmaf(bf_lo(u2.y), w2.z, a2);
            a3 = fmaf(bf_hi(u2.y), w2.w, a3);
            a0 = fmaf(bf_lo(u3.x), w3.x, a0);
            a1 = fmaf(bf_hi(u3.x), w3.y, a1);
            a2 = fmaf(bf_lo(u3.y), w3.z, a2);
            a3 = fmaf(bf_hi(u3.y), w3.w, a3);
        }
    }
    {   // mid * mask -> xs
        const float m = mask[r0 + h];
        float4 o = make_float4(a0 * m, a1 * m, a2 * m, a3 * m);
        *(float4*)&xs[h][p * 4] = o;
    }
    __syncthreads();

    // ---------------- a2 then a3, x resident in LDS ----------------
    const int col = t & 255;
    const int g = t >> 8;              // rows 4g..4g+3
    const int c0 = blockIdx.x & 15;

    float acc[4] = {0.f, 0.f, 0.f, 0.f};
    {
        float w[16], wn[16];
        {
            const int kt = c0 * 16;
            #pragma unroll
            for (int q = 0; q < 16; ++q) w[q] = W_a2[(kt + q) * 256 + col];
        }
        for (int i = 0; i < 16; ++i) {
            const int kt = ((c0 + i) & 15) * 16;
            if (i < 15) {
                const int ktn = ((c0 + i + 1) & 15) * 16;
                #pragma unroll
                for (int q = 0; q < 16; ++q) wn[q] = W_a2[(ktn + q) * 256 + col];
            }
            #pragma unroll
            for (int q4 = 0; q4 < 4; ++q4) {
                const int k = kt + q4 * 4;
                const float w0 = w[q4 * 4 + 0], w1 = w[q4 * 4 + 1];
                const float w2 = w[q4 * 4 + 2], w3 = w[q4 * 4 + 3];
                #pragma unroll
                for (int rr = 0; rr < 4; ++rr) {
                    const float4 xv = *(const float4*)&xs[g * 4 + rr][k];
                    float a = acc[rr];
                    a = fmaf(xv.x, w0, a);
                    a = fmaf(xv.y, w1, a);
                    a = fmaf(xv.z, w2, a);
                    a = fmaf(xv.w, w3, a);
                    acc[rr] = a;
                }
            }
            if (i < 15) {
                #pragma unroll
                for (int q = 0; q < 16; ++q) w[q] = wn[q];
            }
        }
    }
    float y[4];
    {
        const float b2 = b_a2[col];
        #pragma unroll
        for (int rr = 0; rr < 4; ++rr)
            y[rr] = ssp(acc[rr] + b2) * mask[r0 + g * 4 + rr];
    }
    __syncthreads();
    #pragma unroll
    for (int rr = 0; rr < 4; ++rr) xs[g * 4 + rr][col] = y[rr];
    __syncthreads();

    float acc3[4] = {0.f, 0.f, 0.f, 0.f};
    {
        float w[16], wn[16];
        {
            const int kt = c0 * 16;
            #pragma unroll
            for (int q = 0; q < 16; ++q) w[q] = W_a3[(kt + q) * 256 + col];
        }
        for (int i = 0; i < 16; ++i) {
            const int kt = ((c0 + i) & 15) * 16;
            if (i < 15) {
                const int ktn = ((c0 + i + 1) & 15) * 16;
                #pragma unroll
                for (int q = 0; q < 16; ++q) wn[q] = W_a3[(ktn + q) * 256 + col];
            }
            #pragma unroll
            for (int q4 = 0; q4 < 4; ++q4) {
                const int k = kt + q4 * 4;
                const float w0 = w[q4 * 4 + 0], w1 = w[q4 * 4 + 1];
                const float w2 = w[q4 * 4 + 2], w3 = w[q4 * 4 + 3];
                #pragma unroll
                for (int rr = 0; rr < 4; ++rr) {
                    const float4 xv = *(const float4*)&xs[g * 4 + rr][k];
                    float a = acc3[rr];
                    a = fmaf(xv.x, w0, a);
                    a = fmaf(xv.y, w1, a);
                    a = fmaf(xv.z, w2, a);
                    a = fmaf(xv.w, w3, a);
                    acc3[rr] = a;
                }
            }
            if (i < 15) {
                #pragma unroll
                for (int q = 0; q < 16; ++q) w[q] = wn[q];
            }
        }
    }
    {
        const float b3 = b_a3[col];
        #pragma unroll
        for (int rr = 0; rr < 4; ++rr) {
            const int r = r0 + g * 4 + rr;
            out[r * 256 + col] = (acc3[rr] + b3) * mask[r];
        }
    }
}

// ---------------------------------------------------------------------------
extern "C" void kernel_launch(void* const* d_in, const int* in_sizes, int n_in,
                              void* d_out, int out_size, void* d_ws, size_t ws_size,
                              hipStream_t stream) {
    const float* v    = (const float*)d_in[0];
    const float* dist = (const float*)d_in[1];
    const float* mask = (const float*)d_in[2];
    const float* W_s1 = (const float*)d_in[3];
    const float* b_s1 = (const float*)d_in[4];
    const float* W_s2 = (const float*)d_in[5];
    const float* b_s2 = (const float*)d_in[6];
    const float* W_a1 = (const float*)d_in[7];
    const float* b_a1 = (const float*)d_in[8];
    const float* W_a2 = (const float*)d_in[9];
    const float* b_a2 = (const float*)d_in[10];
    const float* W_a3 = (const float*)d_in[11];
    const float* b_a3 = (const float*)d_in[12];
    float* out = (float*)d_out;

    char* ws = (char*)d_ws;
    float*    v1 = (float*)(ws);                   // 2 MB
    uint16_t* T  = (uint16_t*)(ws + (2u << 20));   // 2 MB bf16 [4096][256]

    prep_kernel<<<768, 512, 0, stream>>>(v, mask, W_a1, b_a1, W_s1, b_s1, W_s2, b_s2, v1, T);
    main_kernel<<<256, 512, 0, stream>>>(dist, v1, T, mask, W_a2, b_a2, W_a3, b_a3, out);
}